// Round 1
// baseline (253.278 us; speedup 1.0000x reference)
//
#include <hip/hip_runtime.h>

typedef short bf16x8 __attribute__((ext_vector_type(8)));
typedef float f32x4  __attribute__((ext_vector_type(4)));
typedef unsigned short u16x4 __attribute__((ext_vector_type(4)));

#define DIMN  256
#define NSTEP 25
#define MBLK  64

__device__ __forceinline__ unsigned short f2bf(float x) {
    union { float f; unsigned int u; } v; v.f = x;
    unsigned int r = v.u + 0x7FFFu + ((v.u >> 16) & 1u);   // RNE
    return (unsigned short)(r >> 16);
}

__device__ __forceinline__ float tanh_fast(float x) {
    // tanh(x) = 1 - 2/(e^{2x}+1); saturates correctly at +/-inf of exp
    float e = __expf(2.0f * x);
    return 1.0f - 2.0f * __builtin_amdgcn_rcpf(e + 1.0f);
}

// Build sigma-permuted, fragment-ordered bf16 weights.
// Wr[idx], idx = kc*8192 + n*32 + q*8 + j  <-  W[sigma_inv(kc*32+q*8+j)][n]
// sigma_inv(p) = (p & ~63) | ((p&3)<<4) | ((p>>2)&15)
__global__ void prep_weights(const float* __restrict__ W1,
                             const float* __restrict__ W2,
                             unsigned short* __restrict__ Wr)
{
    int b = blockIdx.x;
    const float* src = (b < 256) ? W1 : W2;
    unsigned short* dst = Wr + ((b < 256) ? 0 : 65536);
    int idx = (b & 255) * 256 + threadIdx.x;   // 0..65535
    int j  = idx & 7;
    int q  = (idx >> 3) & 3;
    int n  = (idx >> 5) & 255;
    int kc = idx >> 13;
    int p  = kc * 32 + q * 8 + j;
    int k  = (p & ~63) | ((p & 3) << 4) | ((p >> 2) & 15);
    dst[idx] = f2bf(src[k * 256 + n]);
}

__global__ __launch_bounds__(256, 1) void ode_main(
    const float* __restrict__ z0,
    const float* __restrict__ t_range,
    const float* __restrict__ b1,
    const float* __restrict__ wt,
    const float* __restrict__ b2,
    const unsigned short* __restrict__ W1r,
    const unsigned short* __restrict__ W2r,
    float* __restrict__ out)
{
    __shared__ __align__(16) unsigned short As[MBLK * DIMN];  // 32 KiB, sigma-ordered bf16

    const int tid  = threadIdx.x;
    const int wave = tid >> 6;        // 0..3 -> col slice [wave*64, wave*64+64)
    const int lane = tid & 63;
    const int q    = lane >> 4;       // quad
    const int l15  = lane & 15;
    const int row0 = blockIdx.x * MBLK;
    const int n0   = wave * 64;

    // per-lane bias values for its 4 natural column indices
    float b1v[4], wtv[4], b2v[4];
#pragma unroll
    for (int tt = 0; tt < 4; ++tt) {
        int n = n0 + tt * 16 + l15;
        b1v[tt] = b1[n];
        wtv[tt] = wt[n];
        b2v[tt] = b2[n];
    }

    const float dt = t_range[1] - t_range[0];

    // z state in MFMA C-layout: z[band][tt][r] = z[row0+band*16+q*4+r][n0+tt*16+l15]
    f32x4 z[4][4];
#pragma unroll
    for (int band = 0; band < 4; ++band)
#pragma unroll
        for (int tt = 0; tt < 4; ++tt)
#pragma unroll
            for (int r = 0; r < 4; ++r)
                z[band][tt][r] =
                    z0[(row0 + band * 16 + q * 4 + r) * DIMN + n0 + tt * 16 + l15];

    for (int s = 0; s < NSTEP; ++s) {
        const float t = t_range[s];

        // ---- stage bf16(z) into As (sigma-permuted cols: one b64 write / row) ----
#pragma unroll
        for (int band = 0; band < 4; ++band)
#pragma unroll
            for (int r = 0; r < 4; ++r) {
                int m = band * 16 + q * 4 + r;
                u16x4 v;
#pragma unroll
                for (int tt = 0; tt < 4; ++tt) v[tt] = f2bf(z[band][tt][r]);
                *(u16x4*)&As[m * DIMN + n0 + l15 * 4] = v;
            }
        __syncthreads();

        // ---- GEMM1: acc = z @ W1  (K = 256, sigma-space) ----
        f32x4 acc[4][4];
#pragma unroll
        for (int band = 0; band < 4; ++band)
#pragma unroll
            for (int tt = 0; tt < 4; ++tt) acc[band][tt] = f32x4{0.f, 0.f, 0.f, 0.f};

#pragma unroll
        for (int kc = 0; kc < 8; ++kc) {
            bf16x8 a[4], bb[4];
#pragma unroll
            for (int band = 0; band < 4; ++band)
                a[band] = *(const bf16x8*)&As[(band * 16 + l15) * DIMN + kc * 32 + q * 8];
#pragma unroll
            for (int tt = 0; tt < 4; ++tt)
                bb[tt] = *(const bf16x8*)&W1r[kc * 8192 + (n0 + tt * 16 + l15) * 32 + q * 8];
#pragma unroll
            for (int band = 0; band < 4; ++band)
#pragma unroll
                for (int tt = 0; tt < 4; ++tt)
                    acc[band][tt] = __builtin_amdgcn_mfma_f32_16x16x32_bf16(
                        a[band], bb[tt], acc[band][tt], 0, 0, 0);
        }

        __syncthreads();   // all A-reads of z done before overwriting As with H

        // ---- H = tanh(acc + b1 + t*wt) -> bf16 -> As ----
#pragma unroll
        for (int band = 0; band < 4; ++band)
#pragma unroll
            for (int r = 0; r < 4; ++r) {
                int m = band * 16 + q * 4 + r;
                u16x4 v;
#pragma unroll
                for (int tt = 0; tt < 4; ++tt) {
                    float x = acc[band][tt][r] + b1v[tt] + t * wtv[tt];
                    v[tt] = f2bf(tanh_fast(x));
                }
                *(u16x4*)&As[m * DIMN + n0 + l15 * 4] = v;
            }
        __syncthreads();

        // ---- GEMM2: acc = H @ W2 ----
#pragma unroll
        for (int band = 0; band < 4; ++band)
#pragma unroll
            for (int tt = 0; tt < 4; ++tt) acc[band][tt] = f32x4{0.f, 0.f, 0.f, 0.f};

#pragma unroll
        for (int kc = 0; kc < 8; ++kc) {
            bf16x8 a[4], bb[4];
#pragma unroll
            for (int band = 0; band < 4; ++band)
                a[band] = *(const bf16x8*)&As[(band * 16 + l15) * DIMN + kc * 32 + q * 8];
#pragma unroll
            for (int tt = 0; tt < 4; ++tt)
                bb[tt] = *(const bf16x8*)&W2r[kc * 8192 + (n0 + tt * 16 + l15) * 32 + q * 8];
#pragma unroll
            for (int band = 0; band < 4; ++band)
#pragma unroll
                for (int tt = 0; tt < 4; ++tt)
                    acc[band][tt] = __builtin_amdgcn_mfma_f32_16x16x32_bf16(
                        a[band], bb[tt], acc[band][tt], 0, 0, 0);
        }

        // ---- z += dt * (acc + b2)  (fp32 state update) ----
#pragma unroll
        for (int band = 0; band < 4; ++band)
#pragma unroll
            for (int tt = 0; tt < 4; ++tt)
#pragma unroll
                for (int r = 0; r < 4; ++r)
                    z[band][tt][r] += dt * (acc[band][tt][r] + b2v[tt]);

        __syncthreads();   // GEMM2 A-reads done before next step's z staging
    }

    // ---- final store (natural layout, fp32) ----
#pragma unroll
    for (int band = 0; band < 4; ++band)
#pragma unroll
        for (int tt = 0; tt < 4; ++tt)
#pragma unroll
            for (int r = 0; r < 4; ++r)
                out[(row0 + band * 16 + q * 4 + r) * DIMN + n0 + tt * 16 + l15] =
                    z[band][tt][r];
}

extern "C" void kernel_launch(void* const* d_in, const int* in_sizes, int n_in,
                              void* d_out, int out_size, void* d_ws, size_t ws_size,
                              hipStream_t stream) {
    const float* z0      = (const float*)d_in[0];
    const float* t_range = (const float*)d_in[1];
    const float* W1      = (const float*)d_in[2];
    const float* b1      = (const float*)d_in[3];
    const float* wt      = (const float*)d_in[4];
    const float* W2      = (const float*)d_in[5];
    const float* b2      = (const float*)d_in[6];
    unsigned short* Wr   = (unsigned short*)d_ws;   // W1r at [0,65536), W2r at [65536,131072)

    prep_weights<<<512, 256, 0, stream>>>(W1, W2, Wr);
    ode_main<<<256, 256, 0, stream>>>(z0, t_range, b1, wt, b2,
                                      Wr, Wr + 65536, (float*)d_out);
}

// Round 2
// 191.342 us; speedup vs baseline: 1.3237x; 1.3237x over previous
//
#include <hip/hip_runtime.h>

typedef short bf16x8 __attribute__((ext_vector_type(8)));
typedef float f32x4  __attribute__((ext_vector_type(4)));

#define NSTEP 25
#define SROW  264               // padded LDS row stride in shorts (132 dwords % 32 banks = 4)
#define LDSB  (64 * SROW)       // shorts per buffer

__device__ __forceinline__ unsigned short f2bf(float x) {
    union { float f; unsigned int u; } v; v.f = x;
    unsigned int r = v.u + 0x7FFFu + ((v.u >> 16) & 1u);   // RNE
    return (unsigned short)(r >> 16);
}

__device__ __forceinline__ float tanh_fast(float x) {
    float e = __expf(2.0f * x);
    return 1.0f - 2.0f * __builtin_amdgcn_rcpf(e + 1.0f);
}

// sigma-permuted, fragment-ordered bf16 weights.
// Wr[idx], idx = kc*8192 + n*32 + q*8 + j  <-  W[sigma_inv(kc*32+q*8+j)][n]
// 32-col-block sigma: sigma_inv(p) = (p & ~31) | ((p&1)<<4) | ((p>>1)&15)
__global__ void prep_weights(const float* __restrict__ W1,
                             const float* __restrict__ W2,
                             unsigned short* __restrict__ Wr)
{
    int b = blockIdx.x;
    const float* src = (b < 256) ? W1 : W2;
    unsigned short* dst = Wr + ((b < 256) ? 0 : 65536);
    int idx = (b & 255) * 256 + threadIdx.x;   // 0..65535
    int j  = idx & 7;
    int q  = (idx >> 3) & 3;
    int n  = (idx >> 5) & 255;
    int kc = idx >> 13;
    int p  = kc * 32 + q * 8 + j;
    int k  = (p & ~31) | ((p & 1) << 4) | ((p >> 1) & 15);
    dst[idx] = f2bf(src[k * 256 + n]);
}

// 512 threads = 8 waves; wave w owns cols [32w, 32w+32) of all 64 rows.
// All weights register-resident: zero global traffic inside the 25-step loop.
__global__ __launch_bounds__(512, 2) void ode_main(
    const float* __restrict__ z0,
    const float* __restrict__ t_range,
    const float* __restrict__ b1,
    const float* __restrict__ wt,
    const float* __restrict__ b2,
    const unsigned short* __restrict__ W1r,
    const unsigned short* __restrict__ W2r,
    float* __restrict__ out)
{
    __shared__ __align__(16) unsigned short As[2 * LDSB];   // 66 KiB, double-buffered

    const int tid  = threadIdx.x;
    const int wave = tid >> 6;        // 0..7 -> col slice [wave*32, wave*32+32)
    const int lane = tid & 63;
    const int q    = lane >> 4;
    const int l15  = lane & 15;
    const int row0 = blockIdx.x * 64;
    const int n0   = wave * 32;

    // ---- preload weight fragments into registers (128 VGPRs) ----
    bf16x8 w1f[8][2], w2f[8][2];
#pragma unroll
    for (int kc = 0; kc < 8; ++kc)
#pragma unroll
        for (int tt = 0; tt < 2; ++tt) {
            int off = kc * 8192 + (n0 + tt * 16 + l15) * 32 + q * 8;
            w1f[kc][tt] = *(const bf16x8*)&W1r[off];
            w2f[kc][tt] = *(const bf16x8*)&W2r[off];
        }

    float b1v[2], wtv[2], b2v[2];
#pragma unroll
    for (int tt = 0; tt < 2; ++tt) {
        int n = n0 + tt * 16 + l15;
        b1v[tt] = b1[n]; wtv[tt] = wt[n]; b2v[tt] = b2[n];
    }

    const float dt = t_range[1] - t_range[0];

    // z state in MFMA C-layout: z[band][tt][r] = z[row0+band*16+q*4+r][n0+tt*16+l15]
    f32x4 z[4][2];
#pragma unroll
    for (int band = 0; band < 4; ++band)
#pragma unroll
        for (int tt = 0; tt < 2; ++tt)
#pragma unroll
            for (int r = 0; r < 4; ++r)
                z[band][tt][r] =
                    z0[(row0 + band * 16 + q * 4 + r) * 256 + n0 + tt * 16 + l15];

    for (int s = 0; s < NSTEP; ++s) {
        const float t = t_range[s];

        // ---- stage bf16(z) -> buf0 (sigma-packed: one b32 write per row) ----
#pragma unroll
        for (int band = 0; band < 4; ++band)
#pragma unroll
            for (int r = 0; r < 4; ++r) {
                int m = band * 16 + q * 4 + r;
                unsigned int v = (unsigned int)f2bf(z[band][0][r])
                               | ((unsigned int)f2bf(z[band][1][r]) << 16);
                *(unsigned int*)&As[m * SROW + n0 + l15 * 2] = v;
            }
        __syncthreads();

        // ---- GEMM1: acc = z @ W1 ----
        f32x4 acc[4][2];
#pragma unroll
        for (int band = 0; band < 4; ++band)
#pragma unroll
            for (int tt = 0; tt < 2; ++tt) acc[band][tt] = f32x4{0.f, 0.f, 0.f, 0.f};

#pragma unroll
        for (int kc = 0; kc < 8; ++kc) {
            bf16x8 a[4];
#pragma unroll
            for (int band = 0; band < 4; ++band)
                a[band] = *(const bf16x8*)&As[(band * 16 + l15) * SROW + kc * 32 + q * 8];
#pragma unroll
            for (int band = 0; band < 4; ++band)
#pragma unroll
                for (int tt = 0; tt < 2; ++tt)
                    acc[band][tt] = __builtin_amdgcn_mfma_f32_16x16x32_bf16(
                        a[band], w1f[kc][tt], acc[band][tt], 0, 0, 0);
        }

        // ---- H = tanh(acc + b1 + t*wt) -> buf1 (no barrier needed: disjoint buffer) ----
#pragma unroll
        for (int band = 0; band < 4; ++band)
#pragma unroll
            for (int r = 0; r < 4; ++r) {
                int m = band * 16 + q * 4 + r;
                float h0 = tanh_fast(acc[band][0][r] + b1v[0] + t * wtv[0]);
                float h1 = tanh_fast(acc[band][1][r] + b1v[1] + t * wtv[1]);
                unsigned int v = (unsigned int)f2bf(h0)
                               | ((unsigned int)f2bf(h1) << 16);
                *(unsigned int*)&As[LDSB + m * SROW + n0 + l15 * 2] = v;
            }
        __syncthreads();

        // ---- GEMM2: acc = H @ W2 ----
#pragma unroll
        for (int band = 0; band < 4; ++band)
#pragma unroll
            for (int tt = 0; tt < 2; ++tt) acc[band][tt] = f32x4{0.f, 0.f, 0.f, 0.f};

#pragma unroll
        for (int kc = 0; kc < 8; ++kc) {
            bf16x8 a[4];
#pragma unroll
            for (int band = 0; band < 4; ++band)
                a[band] = *(const bf16x8*)&As[LDSB + (band * 16 + l15) * SROW + kc * 32 + q * 8];
#pragma unroll
            for (int band = 0; band < 4; ++band)
#pragma unroll
                for (int tt = 0; tt < 2; ++tt)
                    acc[band][tt] = __builtin_amdgcn_mfma_f32_16x16x32_bf16(
                        a[band], w2f[kc][tt], acc[band][tt], 0, 0, 0);
        }

        // ---- z += dt * (acc + b2); no trailing barrier needed (buf0 writers
        //      can't pass next step's post-stage barrier before all GEMM1 readers
        //      of this step finished — guaranteed by this step's 2nd barrier) ----
#pragma unroll
        for (int band = 0; band < 4; ++band)
#pragma unroll
            for (int tt = 0; tt < 2; ++tt)
#pragma unroll
                for (int r = 0; r < 4; ++r)
                    z[band][tt][r] += dt * (acc[band][tt][r] + b2v[tt]);
    }

    // ---- final store (natural layout, fp32) ----
#pragma unroll
    for (int band = 0; band < 4; ++band)
#pragma unroll
        for (int tt = 0; tt < 2; ++tt)
#pragma unroll
            for (int r = 0; r < 4; ++r)
                out[(row0 + band * 16 + q * 4 + r) * 256 + n0 + tt * 16 + l15] =
                    z[band][tt][r];
}

extern "C" void kernel_launch(void* const* d_in, const int* in_sizes, int n_in,
                              void* d_out, int out_size, void* d_ws, size_t ws_size,
                              hipStream_t stream) {
    const float* z0      = (const float*)d_in[0];
    const float* t_range = (const float*)d_in[1];
    const float* W1      = (const float*)d_in[2];
    const float* b1      = (const float*)d_in[3];
    const float* wt      = (const float*)d_in[4];
    const float* W2      = (const float*)d_in[5];
    const float* b2      = (const float*)d_in[6];
    unsigned short* Wr   = (unsigned short*)d_ws;   // W1r at [0,65536), W2r at [65536,131072)

    prep_weights<<<512, 256, 0, stream>>>(W1, W2, Wr);
    ode_main<<<256, 512, 0, stream>>>(z0, t_range, b1, wt, b2,
                                      Wr, Wr + 65536, (float*)d_out);
}